// Round 1
// baseline (416.594 us; speedup 1.0000x reference)
//
#include <hip/hip_runtime.h>

// B=8, H=8, L=2048, D=64, num_delays=16
static constexpr int LSEQ = 2048;
static constexpr int NB   = 8;
static constexpr int NH   = 8;
static constexpr int ND   = 64;
static constexpr int NDEL = 16;

// ws layout:
//   S     : float2[8 b][2048]  at 0        (128 KiB) reduced spectrum, digit-rev order
//           (accumulated via device-scope atomicAdd from all fft_corr blocks)
//   w     : float [8][16]      at 8388608
//   delay : int   [8][16]      at 8389120
static constexpr size_t WS_P_OFF     = 0;
static constexpr size_t WS_W_OFF     = 8388608;
static constexpr size_t WS_DELAY_OFF = 8389120;

// LDS bank swizzle on float2 index: fold bits 4..6 into bits 1..3.
__device__ __forceinline__ int SWZ(int x) { return x ^ (((x >> 4) & 7) << 1); }

// digit-reversed position of frequency f (radices 8,8,8,4 DIF) and inverse
__device__ __forceinline__ int pof(int f) {
    return ((f & 7) << 8) | (((f >> 3) & 7) << 5) | (((f >> 6) & 7) << 2) | (f >> 9);
}
__device__ __forceinline__ int fofp(int p) {
    return (p >> 8) | (((p >> 5) & 7) << 3) | (((p >> 2) & 7) << 6) | ((p & 3) << 9);
}

#define CMUL(ar, ai, br, bi) make_float2((ar)*(br) - (ai)*(bi), (ar)*(bi) + (ai)*(br))

// 8-pt DIF DFT in regs; x[0..7] in, X[0..7] (natural freq order) out.
__device__ __forceinline__ void dft8(const float2 x[8], float2 X[8]) {
    const float RH = 0.70710678118654752440f;
    float2 a0 = make_float2(x[0].x + x[4].x, x[0].y + x[4].y);
    float2 a1 = make_float2(x[1].x + x[5].x, x[1].y + x[5].y);
    float2 a2 = make_float2(x[2].x + x[6].x, x[2].y + x[6].y);
    float2 a3 = make_float2(x[3].x + x[7].x, x[3].y + x[7].y);
    float2 b0 = make_float2(x[0].x - x[4].x, x[0].y - x[4].y);
    float  t1r = x[1].x - x[5].x, t1i = x[1].y - x[5].y;
    float2 b1 = make_float2(RH * (t1r + t1i), RH * (t1i - t1r));       // * w8^1
    float  t2r = x[2].x - x[6].x, t2i = x[2].y - x[6].y;
    float2 b2 = make_float2(t2i, -t2r);                                // * -i
    float  t3r = x[3].x - x[7].x, t3i = x[3].y - x[7].y;
    float2 b3 = make_float2(RH * (t3i - t3r), -RH * (t3r + t3i));      // * w8^3
    float2 c0 = make_float2(a0.x + a2.x, a0.y + a2.y);
    float2 d0 = make_float2(a0.x - a2.x, a0.y - a2.y);
    float2 c1 = make_float2(a1.x + a3.x, a1.y + a3.y);
    float2 d1 = make_float2(a1.y - a3.y, -(a1.x - a3.x));              // * -i
    X[0] = make_float2(c0.x + c1.x, c0.y + c1.y);
    X[4] = make_float2(c0.x - c1.x, c0.y - c1.y);
    X[2] = make_float2(d0.x + d1.x, d0.y + d1.y);
    X[6] = make_float2(d0.x - d1.x, d0.y - d1.y);
    float2 e0 = make_float2(b0.x + b2.x, b0.y + b2.y);
    float2 f0 = make_float2(b0.x - b2.x, b0.y - b2.y);
    float2 e1 = make_float2(b1.x + b3.x, b1.y + b3.y);
    float2 f1 = make_float2(b1.y - b3.y, -(b1.x - b3.x));              // * -i
    X[1] = make_float2(e0.x + e1.x, e0.y + e1.y);
    X[5] = make_float2(e0.x - e1.x, e0.y - e1.y);
    X[3] = make_float2(f0.x + f1.x, f0.y + f1.y);
    X[7] = make_float2(f0.x - f1.x, f0.y - f1.y);
}

// 4-pt DFT: X[m] = sum_j x[j] (-i)^{jm}
__device__ __forceinline__ void dft4(const float2 x[4], float2 X[4]) {
    float2 s0 = make_float2(x[0].x + x[2].x, x[0].y + x[2].y);
    float2 s1 = make_float2(x[1].x + x[3].x, x[1].y + x[3].y);
    float2 d0 = make_float2(x[0].x - x[2].x, x[0].y - x[2].y);
    float2 d1 = make_float2(x[1].y - x[3].y, -(x[1].x - x[3].x));      // * -i
    X[0] = make_float2(s0.x + s1.x, s0.y + s1.y);
    X[2] = make_float2(s0.x - s1.x, s0.y - s1.y);
    X[1] = make_float2(d0.x + d1.x, d0.y + d1.y);
    X[3] = make_float2(d0.x - d1.x, d0.y - d1.y);
}

// in-place radix-8 stage with twiddle chain W on LDS plane zp
__device__ __forceinline__ void stageR8(float2* zp, const int adr[8], const float2 W[7]) {
    float2 X[8], Y[8];
    #pragma unroll
    for (int j = 0; j < 8; ++j) X[j] = zp[adr[j]];
    dft8(X, Y);
    #pragma unroll
    for (int m = 1; m < 8; ++m) Y[m] = CMUL(Y[m].x, Y[m].y, W[m-1].x, W[m-1].y);
    #pragma unroll
    for (int m = 0; m < 8; ++m) zp[adr[m]] = Y[m];
}

// final twiddle-free stage: two radix-4 on 8 consecutive; result also in X
__device__ __forceinline__ void stageD(float2* zp, const int adr[8], float2 X[8]) {
    float2 xin[8];
    #pragma unroll
    for (int j = 0; j < 8; ++j) xin[j] = zp[adr[j]];
    dft4(&xin[0], &X[0]);
    dft4(&xin[4], &X[4]);
    #pragma unroll
    for (int m = 0; m < 8; ++m) zp[adr[m]] = X[m];
}

// ---------------------------------------------------------------------------
// zero the reduced spectrum S (8 b x 2048 float2 = 128 KiB) before atomics
// ---------------------------------------------------------------------------
__global__ __launch_bounds__(256) void zero_S(float4* __restrict__ P4) {
    P4[blockIdx.x * 256 + threadIdx.x] = make_float4(0.f, 0.f, 0.f, 0.f);
}

// ---------------------------------------------------------------------------
// Kernel A: block = (b,h,grp of 8 d-chan, half). Mixed-radix 8*8*8*4 DIF FFT.
// Grid 1024 (vs 512): the former per-block 'half' loop is split across blocks,
// halving the serial 20-barrier chain to 10 and raising residency from
// 2 blocks/CU to 4 (LDS 32 KiB, VGPR<=128 via launch_bounds(256,4)).
// Product accumulates DIRECTLY into the reduced spectrum S[b][2048] with
// device-scope atomicAdd (128 adds/slot, contention trivial) — this removes
// the 64-partial P array AND the reduce_S kernel entirely.
// TWO channels in flight per sync phase (two 16 KiB LDS planes).
// ---------------------------------------------------------------------------
__global__ __launch_bounds__(256, 4) void fft_corr(const float* __restrict__ q,
                                                   const float* __restrict__ k,
                                                   float2* __restrict__ P) {
    __shared__ float2 z0[LSEQ], z1[LSEQ];   // 32 KiB (swizzled)
    const int t    = threadIdx.x;
    const int bi   = blockIdx.x;            // 1024 = 8 xcd * 8 bh * 8 grp * 2 half
    const int xcd  = bi & 7;
    const int sl   = bi >> 3;               // 0..127
    const int bh   = xcd * 8 + (sl >> 4);   // 16 blocks of same bh share an XCD
    const int grp  = (sl >> 1) & 7;
    const int half = sl & 1;
    const int b    = bh >> 3;
    const size_t base = (size_t)bh * LSEQ * ND + (size_t)(grp * 8 + half * 4);

    // twiddle power chains (per thread, shared by all channels)
    float2 WA[7], WB[7], WC[7];
    {
        float sn, cs;
        __sincosf(-6.28318530717958647692f * (float)t / 2048.f, &sn, &cs);
        WA[0] = make_float2(cs, sn);
        __sincosf(-6.28318530717958647692f * (float)(t & 31) / 256.f, &sn, &cs);
        WB[0] = make_float2(cs, sn);
        __sincosf(-6.28318530717958647692f * (float)(t & 3) / 32.f, &sn, &cs);
        WC[0] = make_float2(cs, sn);
        #pragma unroll
        for (int m = 1; m < 7; ++m) {
            WA[m] = CMUL(WA[m-1].x, WA[m-1].y, WA[0].x, WA[0].y);
            WB[m] = CMUL(WB[m-1].x, WB[m-1].y, WB[0].x, WB[0].y);
            WC[m] = CMUL(WC[m-1].x, WC[m-1].y, WC[0].x, WC[0].y);
        }
    }

    // owned product slots: cc in {0,1,4,5} -> f in [0,1024)
    int fS[4], pmS[4];
    #pragma unroll
    for (int s = 0; s < 4; ++s) {
        const int cc = (s < 2) ? s : s + 2;           // {0,1,4,5}
        const int f  = fofp(8 * t + cc);
        const int m  = (2048 - f) & 2047;
        fS[s]  = f;
        pmS[s] = SWZ(pof(m));
    }
    float aFr[4] = {0, 0, 0, 0}, aFi[4] = {0, 0, 0, 0};
    float aS = 0.f;                      // f=1024 special (thread 0)

    const int sbB   = (t >> 5) * 256 + (t & 31);
    const int baseC = (t >> 2) * 32 + (t & 3);
    int adrB[8], adrC[8], adrD[8];
    #pragma unroll
    for (int n = 0; n < 8; ++n) {
        adrB[n] = SWZ(sbB + 32 * n);
        adrC[n] = SWZ(baseC + 4 * n);
        adrD[n] = SWZ(8 * t + n);
    }

    float4 qa[8], ka[8];
    #pragma unroll
    for (int j = 0; j < 8; ++j) {
        const size_t r = base + (size_t)(t + 256 * j) * ND;
        qa[j] = *(const float4*)(q + r);
        ka[j] = *(const float4*)(k + r);
    }
    #pragma unroll
    for (int pr = 0; pr < 2; ++pr) {
        const int c0 = 2 * pr, c1 = 2 * pr + 1;
        float2 X0[8], X1[8], Y0[8], Y1[8];
        #pragma unroll
        for (int j = 0; j < 8; ++j) {
            X0[j] = make_float2((&qa[j].x)[c0], (&ka[j].x)[c0]);
            X1[j] = make_float2((&qa[j].x)[c1], (&ka[j].x)[c1]);
        }
        __syncthreads();             // z planes free (prev pair's readers done)

        // stage A: radix-8 on rows t+256j (from regs), scatter to bands
        dft8(X0, Y0);
        dft8(X1, Y1);
        #pragma unroll
        for (int m = 1; m < 8; ++m) {
            Y0[m] = CMUL(Y0[m].x, Y0[m].y, WA[m-1].x, WA[m-1].y);
            Y1[m] = CMUL(Y1[m].x, Y1[m].y, WA[m-1].x, WA[m-1].y);
        }
        #pragma unroll
        for (int m = 0; m < 8; ++m) {
            const int a = SWZ(m * 256 + t);
            z0[a] = Y0[m];
            z1[a] = Y1[m];
        }
        __syncthreads();

        stageR8(z0, adrB, WB);
        stageR8(z1, adrB, WB);
        __syncthreads();

        stageR8(z0, adrC, WC);
        stageR8(z1, adrC, WC);
        __syncthreads();

        stageD(z0, adrD, X0);
        stageD(z1, adrD, X1);
        __syncthreads();

        // product: acc Q[f] conj(K[f]) for 4 owned slots (+f=1024)
        #pragma unroll
        for (int s = 0; s < 4; ++s) {
            const int cc = (s < 2) ? s : s + 2;   // {0,1,4,5}
            {
                const float2 Zf = X0[cc], Zm = z0[pmS[s]];
                const float qr = 0.5f * (Zf.x + Zm.x), qi = 0.5f * (Zf.y - Zm.y);
                const float kr = 0.5f * (Zf.y + Zm.y), ki = 0.5f * (Zm.x - Zf.x);
                aFr[s] += qr * kr + qi * ki;
                aFi[s] += qi * kr - qr * ki;
            }
            {
                const float2 Zf = X1[cc], Zm = z1[pmS[s]];
                const float qr = 0.5f * (Zf.x + Zm.x), qi = 0.5f * (Zf.y - Zm.y);
                const float kr = 0.5f * (Zf.y + Zm.y), ki = 0.5f * (Zm.x - Zf.x);
                aFr[s] += qr * kr + qi * ki;
                aFi[s] += qi * kr - qr * ki;
            }
        }
        if (t == 0) aS += X0[2].x * X0[2].y + X1[2].x * X1[2].y;
    }

    // accumulate into reduced spectrum S[b][2048] (digit-rev order).
    // direct slot for cc is 8t+cc; mirrors go to pof(2048-f) (disjoint cc set).
    float2* Pp = P + (size_t)b * 2048;
    #pragma unroll
    for (int s = 0; s < 4; ++s) {
        const int cc = (s < 2) ? s : s + 2;
        float* pd = (float*)(Pp + (8 * t + cc));
        atomicAdd(pd,     aFr[s]);
        atomicAdd(pd + 1, aFi[s]);
        const int m = (2048 - fS[s]) & 2047;
        if (m != fS[s]) {
            float* pm = (float*)(Pp + pof(m));
            atomicAdd(pm,     aFr[s]);
            atomicAdd(pm + 1, -aFi[s]);
        }
    }
    if (t == 0) atomicAdd((float*)(Pp + 2 /*pof(1024)*/), aS);
}

// ---------------------------------------------------------------------------
// Kernel B: block per batch, 256 threads. Inverse FFT via conj trick on the
// SAME verified mixed-radix pipeline: irfft(S)[tau] = Re(FFT_fwd(conj(S))[tau])/N.
// Gather conj(S) from digit-rev slots into stage-A registers, 3 LDS round
// trips, scatter mc to natural tau, then 16-iter argmax top-k + softmax.
// ---------------------------------------------------------------------------
__global__ __launch_bounds__(256) void ifft_topk(const float2* __restrict__ S,
                                                 float* __restrict__ wout,
                                                 int* __restrict__ dout) {
    __shared__ float2 zz[LSEQ];          // 16 KiB work (swizzled in stages)
    __shared__ float  mc[LSEQ];          // 8 KiB, natural tau order
    __shared__ float  pv[4];
    __shared__ int    pig[4];
    __shared__ float  topv[NDEL];
    __shared__ int    topi[NDEL];
    const int b = blockIdx.x, t = threadIdx.x;

    float2 WA[7], WB[7], WC[7];
    {
        float sn, cs;
        __sincosf(-6.28318530717958647692f * (float)t / 2048.f, &sn, &cs);
        WA[0] = make_float2(cs, sn);
        __sincosf(-6.28318530717958647692f * (float)(t & 31) / 256.f, &sn, &cs);
        WB[0] = make_float2(cs, sn);
        __sincosf(-6.28318530717958647692f * (float)(t & 3) / 32.f, &sn, &cs);
        WC[0] = make_float2(cs, sn);
        #pragma unroll
        for (int m = 1; m < 7; ++m) {
            WA[m] = CMUL(WA[m-1].x, WA[m-1].y, WA[0].x, WA[0].y);
            WB[m] = CMUL(WB[m-1].x, WB[m-1].y, WB[0].x, WB[0].y);
            WC[m] = CMUL(WC[m-1].x, WC[m-1].y, WC[0].x, WC[0].y);
        }
    }
    const int sbB   = (t >> 5) * 256 + (t & 31);
    const int baseC = (t >> 2) * 32 + (t & 3);
    int adrB[8], adrC[8], adrD[8];
    #pragma unroll
    for (int n = 0; n < 8; ++n) {
        adrB[n] = SWZ(sbB + 32 * n);
        adrC[n] = SWZ(baseC + 4 * n);
        adrD[n] = SWZ(8 * t + n);
    }

    // coalesced load of S (digit-rev slots) into zz (non-swizzled slots)
    #pragma unroll
    for (int j = 0; j < 8; ++j) zz[t + 256 * j] = S[b * 2048 + t + 256 * j];
    __syncthreads();

    // gather stage-A operands: x[f] = conj(S[f]) at slot pof(f), f = t+256j
    float2 X[8], Y[8];
    #pragma unroll
    for (int j = 0; j < 8; ++j) {
        const float2 s = zz[pof(t + 256 * j)];
        X[j] = make_float2(s.x, -s.y);
    }
    __syncthreads();                     // all gathers done before scatter

    dft8(X, Y);
    #pragma unroll
    for (int m = 1; m < 8; ++m) Y[m] = CMUL(Y[m].x, Y[m].y, WA[m-1].x, WA[m-1].y);
    #pragma unroll
    for (int m = 0; m < 8; ++m) zz[SWZ(m * 256 + t)] = Y[m];
    __syncthreads();

    stageR8(zz, adrB, WB);
    __syncthreads();
    stageR8(zz, adrC, WC);
    __syncthreads();

    // stage D in regs only (no writeback needed)
    {
        float2 xin[8];
        #pragma unroll
        for (int j = 0; j < 8; ++j) xin[j] = zz[adrD[j]];
        dft4(&xin[0], &X[0]);
        dft4(&xin[4], &X[4]);
    }

    // mc[tau] = Re(out)/(L*H*D); slot 8t+cc holds tau = fofp(8t+cc)
    const float scale = 1.0f / ((float)LSEQ * (float)(NH * ND));
    #pragma unroll
    for (int cc = 0; cc < 8; ++cc) mc[fofp(8 * t + cc)] = X[cc].x * scale;
    __syncthreads();

    // top-16 by iterative argmax (ties -> smaller tau)
    const int lane = t & 63, wv = t >> 6;
    for (int it = 0; it < NDEL; ++it) {
        float bv = -3e38f; int bix = 0;
        #pragma unroll
        for (int u = 0; u < 8; ++u) {
            const int idx = t + 256 * u;
            const float v = mc[idx];
            if (v > bv || (v == bv && idx < bix)) { bv = v; bix = idx; }
        }
        #pragma unroll
        for (int off = 32; off; off >>= 1) {
            const float ov = __shfl_xor(bv, off);
            const int   oi = __shfl_xor(bix, off);
            if (ov > bv || (ov == bv && oi < bix)) { bv = ov; bix = oi; }
        }
        if (lane == 0) { pv[wv] = bv; pig[wv] = bix; }
        __syncthreads();
        if (t < 64) {
            float v = (t < 4) ? pv[t] : -3e38f;
            int  ii = (t < 4) ? pig[t] : 0;
            #pragma unroll
            for (int off = 2; off; off >>= 1) {
                const float ov = __shfl_xor(v, off);
                const int   oi = __shfl_xor(ii, off);
                if (ov > v || (ov == v && oi < ii)) { v = ov; ii = oi; }
            }
            if (t == 0) { topv[it] = v; topi[it] = ii; mc[ii] = -3e38f; }
        }
        __syncthreads();
    }

    if (t == 0) {
        const float m = topv[0];
        float e[NDEL], sum = 0.f;
        for (int i = 0; i < NDEL; ++i) { e[i] = __expf(topv[i] - m); sum += e[i]; }
        const float inv = 1.0f / sum;
        for (int i = 0; i < NDEL; ++i) {
            wout[b * NDEL + i] = e[i] * inv;
            dout[b * NDEL + i] = topi[i];
        }
    }
}

// ---------------------------------------------------------------------------
// Kernel C: out[b,h,t,d] = sum_k w[b,k] * v[b,h,(t+delay[b,k]) & 2047, d]
// XCD swizzle: 128 t-tiles of one (b,h) share an XCD (v slice L2-resident).
// ---------------------------------------------------------------------------
__global__ __launch_bounds__(256) void gather_out(const float* __restrict__ v,
                                                  const float* __restrict__ w,
                                                  const int* __restrict__ delay,
                                                  float* __restrict__ out) {
    const int bi  = blockIdx.x;          // 8192 = 64 bh * 128 tiles
    const int xcd = bi & 7;
    const int s   = bi >> 3;
    const int bh  = xcd * 8 + (s >> 7);
    const int bt  = s & 127;
    const int b   = bh >> 3;
    const int tid = threadIdx.x;

    __shared__ float sw_[NDEL];
    __shared__ int   sd_[NDEL];
    if (tid < NDEL) {
        sw_[tid] = w[b * NDEL + tid];
        sd_[tid] = delay[b * NDEL + tid];
    }
    __syncthreads();

    const float* vb = v + (size_t)bh * LSEQ * ND;
    float*       ob = out + (size_t)bh * LSEQ * ND;

    const int row = tid >> 4;
    const int col = (tid & 15) * 4;
    const int t   = bt * 16 + row;

    float4 acc = make_float4(0.f, 0.f, 0.f, 0.f);
    #pragma unroll
    for (int kk = 0; kk < NDEL; ++kk) {
        const int r = (t + sd_[kk]) & (LSEQ - 1);
        const float4 vv = *(const float4*)(vb + (size_t)r * ND + col);
        const float wv = sw_[kk];
        acc.x += wv * vv.x; acc.y += wv * vv.y;
        acc.z += wv * vv.z; acc.w += wv * vv.w;
    }
    *(float4*)(ob + (size_t)t * ND + col) = acc;
}

// ---------------------------------------------------------------------------
extern "C" void kernel_launch(void* const* d_in, const int* in_sizes, int n_in,
                              void* d_out, int out_size, void* d_ws, size_t ws_size,
                              hipStream_t stream) {
    const float* q = (const float*)d_in[0];
    const float* k = (const float*)d_in[1];
    const float* v = (const float*)d_in[2];
    float* out = (float*)d_out;

    float2* P     = (float2*)((char*)d_ws + WS_P_OFF);
    float*  w     = (float*)((char*)d_ws + WS_W_OFF);
    int*    delay = (int*)((char*)d_ws + WS_DELAY_OFF);

    // zero the 128 KiB reduced spectrum (ws is poisoned between runs)
    zero_S<<<dim3(32), dim3(256), 0, stream>>>((float4*)P);
    fft_corr<<<dim3(1024), dim3(256), 0, stream>>>(q, k, P);
    ifft_topk<<<dim3(NB), dim3(256), 0, stream>>>(P, w, delay);
    gather_out<<<dim3(NB * NH * 128), dim3(256), 0, stream>>>(v, w, delay, out);
}

// Round 2
// 231.982 us; speedup vs baseline: 1.7958x; 1.7958x over previous
//
#include <hip/hip_runtime.h>

// B=8, H=8, L=2048, D=64, num_delays=16
static constexpr int LSEQ = 2048;
static constexpr int NB   = 8;
static constexpr int NH   = 8;
static constexpr int ND   = 64;
static constexpr int NDEL = 16;

// ws layout (8.4 MiB total — proven-safe size):
//   P     : float2[64 part][8 b][2048]  at 0        (8 MiB) partial spectra, digit-rev order
//           (after reduce_S, part 0 holds the reduced spectrum S in-place)
//   w     : float [8][16]               at 8388608
//   delay : int   [8][16]               at 8389120
static constexpr size_t WS_P_OFF     = 0;
static constexpr size_t WS_W_OFF     = 8388608;
static constexpr size_t WS_DELAY_OFF = 8389120;

// LDS bank swizzle on float2 index: fold bits 4..6 into bits 1..3.
__device__ __forceinline__ int SWZ(int x) { return x ^ (((x >> 4) & 7) << 1); }

// digit-reversed position of frequency f (radices 8,8,8,4 DIF) and inverse
__device__ __forceinline__ int pof(int f) {
    return ((f & 7) << 8) | (((f >> 3) & 7) << 5) | (((f >> 6) & 7) << 2) | (f >> 9);
}
__device__ __forceinline__ int fofp(int p) {
    return (p >> 8) | (((p >> 5) & 7) << 3) | (((p >> 2) & 7) << 6) | ((p & 3) << 9);
}

#define CMUL(ar, ai, br, bi) make_float2((ar)*(br) - (ai)*(bi), (ar)*(bi) + (ai)*(br))

// 8-pt DIF DFT in regs; x[0..7] in, X[0..7] (natural freq order) out.
__device__ __forceinline__ void dft8(const float2 x[8], float2 X[8]) {
    const float RH = 0.70710678118654752440f;
    float2 a0 = make_float2(x[0].x + x[4].x, x[0].y + x[4].y);
    float2 a1 = make_float2(x[1].x + x[5].x, x[1].y + x[5].y);
    float2 a2 = make_float2(x[2].x + x[6].x, x[2].y + x[6].y);
    float2 a3 = make_float2(x[3].x + x[7].x, x[3].y + x[7].y);
    float2 b0 = make_float2(x[0].x - x[4].x, x[0].y - x[4].y);
    float  t1r = x[1].x - x[5].x, t1i = x[1].y - x[5].y;
    float2 b1 = make_float2(RH * (t1r + t1i), RH * (t1i - t1r));       // * w8^1
    float  t2r = x[2].x - x[6].x, t2i = x[2].y - x[6].y;
    float2 b2 = make_float2(t2i, -t2r);                                // * -i
    float  t3r = x[3].x - x[7].x, t3i = x[3].y - x[7].y;
    float2 b3 = make_float2(RH * (t3i - t3r), -RH * (t3r + t3i));      // * w8^3
    float2 c0 = make_float2(a0.x + a2.x, a0.y + a2.y);
    float2 d0 = make_float2(a0.x - a2.x, a0.y - a2.y);
    float2 c1 = make_float2(a1.x + a3.x, a1.y + a3.y);
    float2 d1 = make_float2(a1.y - a3.y, -(a1.x - a3.x));              // * -i
    X[0] = make_float2(c0.x + c1.x, c0.y + c1.y);
    X[4] = make_float2(c0.x - c1.x, c0.y - c1.y);
    X[2] = make_float2(d0.x + d1.x, d0.y + d1.y);
    X[6] = make_float2(d0.x - d1.x, d0.y - d1.y);
    float2 e0 = make_float2(b0.x + b2.x, b0.y + b2.y);
    float2 f0 = make_float2(b0.x - b2.x, b0.y - b2.y);
    float2 e1 = make_float2(b1.x + b3.x, b1.y + b3.y);
    float2 f1 = make_float2(b1.y - b3.y, -(b1.x - b3.x));              // * -i
    X[1] = make_float2(e0.x + e1.x, e0.y + e1.y);
    X[5] = make_float2(e0.x - e1.x, e0.y - e1.y);
    X[3] = make_float2(f0.x + f1.x, f0.y + f1.y);
    X[7] = make_float2(f0.x - f1.x, f0.y - f1.y);
}

// 4-pt DFT: X[m] = sum_j x[j] (-i)^{jm}
__device__ __forceinline__ void dft4(const float2 x[4], float2 X[4]) {
    float2 s0 = make_float2(x[0].x + x[2].x, x[0].y + x[2].y);
    float2 s1 = make_float2(x[1].x + x[3].x, x[1].y + x[3].y);
    float2 d0 = make_float2(x[0].x - x[2].x, x[0].y - x[2].y);
    float2 d1 = make_float2(x[1].y - x[3].y, -(x[1].x - x[3].x));      // * -i
    X[0] = make_float2(s0.x + s1.x, s0.y + s1.y);
    X[2] = make_float2(s0.x - s1.x, s0.y - s1.y);
    X[1] = make_float2(d0.x + d1.x, d0.y + d1.y);
    X[3] = make_float2(d0.x - d1.x, d0.y - d1.y);
}

// in-place radix-8 stage with twiddle chain W on LDS plane zp
__device__ __forceinline__ void stageR8(float2* zp, const int adr[8], const float2 W[7]) {
    float2 X[8], Y[8];
    #pragma unroll
    for (int j = 0; j < 8; ++j) X[j] = zp[adr[j]];
    dft8(X, Y);
    #pragma unroll
    for (int m = 1; m < 8; ++m) Y[m] = CMUL(Y[m].x, Y[m].y, W[m-1].x, W[m-1].y);
    #pragma unroll
    for (int m = 0; m < 8; ++m) zp[adr[m]] = Y[m];
}

// final twiddle-free stage: two radix-4 on 8 consecutive; result also in X
__device__ __forceinline__ void stageD(float2* zp, const int adr[8], float2 X[8]) {
    float2 xin[8];
    #pragma unroll
    for (int j = 0; j < 8; ++j) xin[j] = zp[adr[j]];
    dft4(&xin[0], &X[0]);
    dft4(&xin[4], &X[4]);
    #pragma unroll
    for (int m = 0; m < 8; ++m) zp[adr[m]] = X[m];
}

// ---------------------------------------------------------------------------
// Kernel A: 512-thread block = (b,h,grp of 8 d-channels). Mixed-radix
// 8*8*8*4 DIF FFT. The two 4-channel halves (former per-block 'half' loop)
// run CONCURRENTLY as two 256-thread half-groups on private LDS plane pairs
// (4 x 16 KiB planes = 64 KiB -> 2 blocks/CU, 16 waves/CU = 2x round-0
// occupancy; serial barrier chain halved 20 -> 10). Halves combine their
// product accumulators via one in-LDS reduction, then half 0 does the same
// round-0 store: 64 private partials, NO atomics (the round-1 atomic
// experiment caused 265 MB of L2-bypass write-through and a 4.5x regression).
// ---------------------------------------------------------------------------
__global__ __launch_bounds__(512, 4) void fft_corr(const float* __restrict__ q,
                                                   const float* __restrict__ k,
                                                   float2* __restrict__ P) {
    __shared__ float2 z[4][LSEQ];           // 64 KiB (swizzled planes)
    const int t   = threadIdx.x;
    const int tl  = t & 255;                // lane within half-group
    const int hf  = t >> 8;                 // which 4-channel half
    const int bi  = blockIdx.x;             // 512 = 8 xcd * 8 bh * 8 grp
    const int xcd = bi & 7;
    const int sl  = bi >> 3;
    const int bh  = xcd * 8 + (sl >> 3);
    const int grp = sl & 7;
    const int b   = bh >> 3;
    const int h   = bh & 7;
    const size_t base = (size_t)bh * LSEQ * ND + (size_t)(grp * 8 + hf * 4);

    float2* const p0 = z[2 * hf];
    float2* const p1 = z[2 * hf + 1];

    // twiddle power chains (per thread, shared by both channels of the pair)
    float2 WA[7], WB[7], WC[7];
    {
        float sn, cs;
        __sincosf(-6.28318530717958647692f * (float)tl / 2048.f, &sn, &cs);
        WA[0] = make_float2(cs, sn);
        __sincosf(-6.28318530717958647692f * (float)(tl & 31) / 256.f, &sn, &cs);
        WB[0] = make_float2(cs, sn);
        __sincosf(-6.28318530717958647692f * (float)(tl & 3) / 32.f, &sn, &cs);
        WC[0] = make_float2(cs, sn);
        #pragma unroll
        for (int m = 1; m < 7; ++m) {
            WA[m] = CMUL(WA[m-1].x, WA[m-1].y, WA[0].x, WA[0].y);
            WB[m] = CMUL(WB[m-1].x, WB[m-1].y, WB[0].x, WB[0].y);
            WC[m] = CMUL(WC[m-1].x, WC[m-1].y, WC[0].x, WC[0].y);
        }
    }

    // owned product slots: cc in {0,1,4,5} -> f in [0,1024)
    int fS[4], pmS[4];
    #pragma unroll
    for (int s = 0; s < 4; ++s) {
        const int cc = (s < 2) ? s : s + 2;           // {0,1,4,5}
        const int f  = fofp(8 * tl + cc);
        const int m  = (2048 - f) & 2047;
        fS[s]  = f;
        pmS[s] = SWZ(pof(m));
    }
    float aFr[4] = {0, 0, 0, 0}, aFi[4] = {0, 0, 0, 0};
    float aS = 0.f;                      // f=1024 special (tl 0 of each half)

    const int sbB   = (tl >> 5) * 256 + (tl & 31);
    const int baseC = (tl >> 2) * 32 + (tl & 3);
    int adrB[8], adrC[8], adrD[8];
    #pragma unroll
    for (int n = 0; n < 8; ++n) {
        adrB[n] = SWZ(sbB + 32 * n);
        adrC[n] = SWZ(baseC + 4 * n);
        adrD[n] = SWZ(8 * tl + n);
    }

    float4 qa[8], ka[8];
    #pragma unroll
    for (int j = 0; j < 8; ++j) {
        const size_t r = base + (size_t)(tl + 256 * j) * ND;
        qa[j] = *(const float4*)(q + r);
        ka[j] = *(const float4*)(k + r);
    }
    #pragma unroll
    for (int pr = 0; pr < 2; ++pr) {
        const int c0 = 2 * pr, c1 = 2 * pr + 1;
        float2 X0[8], X1[8], Y0[8], Y1[8];
        #pragma unroll
        for (int j = 0; j < 8; ++j) {
            X0[j] = make_float2((&qa[j].x)[c0], (&ka[j].x)[c0]);
            X1[j] = make_float2((&qa[j].x)[c1], (&ka[j].x)[c1]);
        }
        __syncthreads();             // z planes free (prev pair's readers done)

        // stage A: radix-8 on rows tl+256j (from regs), scatter to bands
        dft8(X0, Y0);
        dft8(X1, Y1);
        #pragma unroll
        for (int m = 1; m < 8; ++m) {
            Y0[m] = CMUL(Y0[m].x, Y0[m].y, WA[m-1].x, WA[m-1].y);
            Y1[m] = CMUL(Y1[m].x, Y1[m].y, WA[m-1].x, WA[m-1].y);
        }
        #pragma unroll
        for (int m = 0; m < 8; ++m) {
            const int a = SWZ(m * 256 + tl);
            p0[a] = Y0[m];
            p1[a] = Y1[m];
        }
        __syncthreads();

        stageR8(p0, adrB, WB);
        stageR8(p1, adrB, WB);
        __syncthreads();

        stageR8(p0, adrC, WC);
        stageR8(p1, adrC, WC);
        __syncthreads();

        stageD(p0, adrD, X0);
        stageD(p1, adrD, X1);
        __syncthreads();

        // product: acc Q[f] conj(K[f]) for 4 owned slots (+f=1024)
        #pragma unroll
        for (int s = 0; s < 4; ++s) {
            const int cc = (s < 2) ? s : s + 2;   // {0,1,4,5}
            {
                const float2 Zf = X0[cc], Zm = p0[pmS[s]];
                const float qr = 0.5f * (Zf.x + Zm.x), qi = 0.5f * (Zf.y - Zm.y);
                const float kr = 0.5f * (Zf.y + Zm.y), ki = 0.5f * (Zm.x - Zf.x);
                aFr[s] += qr * kr + qi * ki;
                aFi[s] += qi * kr - qr * ki;
            }
            {
                const float2 Zf = X1[cc], Zm = p1[pmS[s]];
                const float qr = 0.5f * (Zf.x + Zm.x), qi = 0.5f * (Zf.y - Zm.y);
                const float kr = 0.5f * (Zf.y + Zm.y), ki = 0.5f * (Zm.x - Zf.x);
                aFr[s] += qr * kr + qi * ki;
                aFi[s] += qi * kr - qr * ki;
            }
        }
        if (tl == 0) aS += X0[2].x * X0[2].y + X1[2].x * X1[2].y;
    }

    // cross-half reduction of the accumulators (half 1 -> LDS -> half 0)
    __syncthreads();                     // product reads of z planes done
    float4* const rb4 = (float4*)&z[0][0];           // 8 KiB scratch in plane 0
    float*  const rbS = (float*)&z[1][0];
    if (hf == 1) {
        rb4[2 * tl]     = make_float4(aFr[0], aFi[0], aFr[1], aFi[1]);
        rb4[2 * tl + 1] = make_float4(aFr[2], aFi[2], aFr[3], aFi[3]);
        if (tl == 0) rbS[0] = aS;
    }
    __syncthreads();
    if (hf == 0) {
        const float4 r0 = rb4[2 * tl], r1 = rb4[2 * tl + 1];
        aFr[0] += r0.x; aFi[0] += r0.y; aFr[1] += r0.z; aFi[1] += r0.w;
        aFr[2] += r1.x; aFi[2] += r1.y; aFr[3] += r1.z; aFi[3] += r1.w;
        if (tl == 0) aS += rbS[0];

        // stores: direct slots contiguous; mirrors conj-scattered (disjoint)
        const int part = h * 8 + grp;
        float2* Pp = P + (size_t)part * (NB * 2048) + (size_t)b * 2048;
        *(float4*)&Pp[8 * tl]     = make_float4(aFr[0], aFi[0], aFr[1], aFi[1]);
        *(float4*)&Pp[8 * tl + 4] = make_float4(aFr[2], aFi[2], aFr[3], aFi[3]);
        #pragma unroll
        for (int s = 0; s < 4; ++s) {
            const int m = (2048 - fS[s]) & 2047;
            if (m != fS[s]) Pp[pof(m)] = make_float2(aFr[s], -aFi[s]);
        }
        if (tl == 0) Pp[pof(1024)] = make_float2(aS, 0.f);
    }
}

// ---------------------------------------------------------------------------
// Reduce 64 partials IN-PLACE into part 0 (thread g owns column g — race-free).
// 64 blocks x 256 spreads the 8 MiB read over many CUs.
// ---------------------------------------------------------------------------
__global__ __launch_bounds__(256) void reduce_S(float2* __restrict__ P) {
    const int g = blockIdx.x * 256 + threadIdx.x;    // 0..16383 = b*2048+pos
    float ax = 0.f, ay = 0.f;
    #pragma unroll 8
    for (int part = 0; part < 64; ++part) {
        const float2 v = P[(size_t)part * (NB * 2048) + g];
        ax += v.x; ay += v.y;
    }
    P[g] = make_float2(ax, ay);
}

// ---------------------------------------------------------------------------
// Kernel B: block per batch, 256 threads. Inverse FFT via conj trick on the
// SAME verified mixed-radix pipeline: irfft(S)[tau] = Re(FFT_fwd(conj(S))[tau])/N.
// Gather conj(S) from digit-rev slots into stage-A registers, 3 LDS round
// trips, scatter mc to natural tau, then 16-iter argmax top-k + softmax.
// ---------------------------------------------------------------------------
__global__ __launch_bounds__(256) void ifft_topk(const float2* __restrict__ S,
                                                 float* __restrict__ wout,
                                                 int* __restrict__ dout) {
    __shared__ float2 zz[LSEQ];          // 16 KiB work (swizzled in stages)
    __shared__ float  mc[LSEQ];          // 8 KiB, natural tau order
    __shared__ float  pv[4];
    __shared__ int    pig[4];
    __shared__ float  topv[NDEL];
    __shared__ int    topi[NDEL];
    const int b = blockIdx.x, t = threadIdx.x;

    float2 WA[7], WB[7], WC[7];
    {
        float sn, cs;
        __sincosf(-6.28318530717958647692f * (float)t / 2048.f, &sn, &cs);
        WA[0] = make_float2(cs, sn);
        __sincosf(-6.28318530717958647692f * (float)(t & 31) / 256.f, &sn, &cs);
        WB[0] = make_float2(cs, sn);
        __sincosf(-6.28318530717958647692f * (float)(t & 3) / 32.f, &sn, &cs);
        WC[0] = make_float2(cs, sn);
        #pragma unroll
        for (int m = 1; m < 7; ++m) {
            WA[m] = CMUL(WA[m-1].x, WA[m-1].y, WA[0].x, WA[0].y);
            WB[m] = CMUL(WB[m-1].x, WB[m-1].y, WB[0].x, WB[0].y);
            WC[m] = CMUL(WC[m-1].x, WC[m-1].y, WC[0].x, WC[0].y);
        }
    }
    const int sbB   = (t >> 5) * 256 + (t & 31);
    const int baseC = (t >> 2) * 32 + (t & 3);
    int adrB[8], adrC[8], adrD[8];
    #pragma unroll
    for (int n = 0; n < 8; ++n) {
        adrB[n] = SWZ(sbB + 32 * n);
        adrC[n] = SWZ(baseC + 4 * n);
        adrD[n] = SWZ(8 * t + n);
    }

    // coalesced load of S (digit-rev slots) into zz (non-swizzled slots)
    #pragma unroll
    for (int j = 0; j < 8; ++j) zz[t + 256 * j] = S[b * 2048 + t + 256 * j];
    __syncthreads();

    // gather stage-A operands: x[f] = conj(S[f]) at slot pof(f), f = t+256j
    float2 X[8], Y[8];
    #pragma unroll
    for (int j = 0; j < 8; ++j) {
        const float2 s = zz[pof(t + 256 * j)];
        X[j] = make_float2(s.x, -s.y);
    }
    __syncthreads();                     // all gathers done before scatter

    dft8(X, Y);
    #pragma unroll
    for (int m = 1; m < 8; ++m) Y[m] = CMUL(Y[m].x, Y[m].y, WA[m-1].x, WA[m-1].y);
    #pragma unroll
    for (int m = 0; m < 8; ++m) zz[SWZ(m * 256 + t)] = Y[m];
    __syncthreads();

    stageR8(zz, adrB, WB);
    __syncthreads();
    stageR8(zz, adrC, WC);
    __syncthreads();

    // stage D in regs only (no writeback needed)
    {
        float2 xin[8];
        #pragma unroll
        for (int j = 0; j < 8; ++j) xin[j] = zz[adrD[j]];
        dft4(&xin[0], &X[0]);
        dft4(&xin[4], &X[4]);
    }

    // mc[tau] = Re(out)/(L*H*D); slot 8t+cc holds tau = fofp(8t+cc)
    const float scale = 1.0f / ((float)LSEQ * (float)(NH * ND));
    #pragma unroll
    for (int cc = 0; cc < 8; ++cc) mc[fofp(8 * t + cc)] = X[cc].x * scale;
    __syncthreads();

    // top-16 by iterative argmax (ties -> smaller tau)
    const int lane = t & 63, wv = t >> 6;
    for (int it = 0; it < NDEL; ++it) {
        float bv = -3e38f; int bix = 0;
        #pragma unroll
        for (int u = 0; u < 8; ++u) {
            const int idx = t + 256 * u;
            const float v = mc[idx];
            if (v > bv || (v == bv && idx < bix)) { bv = v; bix = idx; }
        }
        #pragma unroll
        for (int off = 32; off; off >>= 1) {
            const float ov = __shfl_xor(bv, off);
            const int   oi = __shfl_xor(bix, off);
            if (ov > bv || (ov == bv && oi < bix)) { bv = ov; bix = oi; }
        }
        if (lane == 0) { pv[wv] = bv; pig[wv] = bix; }
        __syncthreads();
        if (t < 64) {
            float v = (t < 4) ? pv[t] : -3e38f;
            int  ii = (t < 4) ? pig[t] : 0;
            #pragma unroll
            for (int off = 2; off; off >>= 1) {
                const float ov = __shfl_xor(v, off);
                const int   oi = __shfl_xor(ii, off);
                if (ov > v || (ov == v && oi < ii)) { v = ov; ii = oi; }
            }
            if (t == 0) { topv[it] = v; topi[it] = ii; mc[ii] = -3e38f; }
        }
        __syncthreads();
    }

    if (t == 0) {
        const float m = topv[0];
        float e[NDEL], sum = 0.f;
        for (int i = 0; i < NDEL; ++i) { e[i] = __expf(topv[i] - m); sum += e[i]; }
        const float inv = 1.0f / sum;
        for (int i = 0; i < NDEL; ++i) {
            wout[b * NDEL + i] = e[i] * inv;
            dout[b * NDEL + i] = topi[i];
        }
    }
}

// ---------------------------------------------------------------------------
// Kernel C: out[b,h,t,d] = sum_k w[b,k] * v[b,h,(t+delay[b,k]) & 2047, d]
// XCD swizzle: 128 t-tiles of one (b,h) share an XCD (v slice L2-resident).
// ---------------------------------------------------------------------------
__global__ __launch_bounds__(256) void gather_out(const float* __restrict__ v,
                                                  const float* __restrict__ w,
                                                  const int* __restrict__ delay,
                                                  float* __restrict__ out) {
    const int bi  = blockIdx.x;          // 8192 = 64 bh * 128 tiles
    const int xcd = bi & 7;
    const int s   = bi >> 3;
    const int bh  = xcd * 8 + (s >> 7);
    const int bt  = s & 127;
    const int b   = bh >> 3;
    const int tid = threadIdx.x;

    __shared__ float sw_[NDEL];
    __shared__ int   sd_[NDEL];
    if (tid < NDEL) {
        sw_[tid] = w[b * NDEL + tid];
        sd_[tid] = delay[b * NDEL + tid];
    }
    __syncthreads();

    const float* vb = v + (size_t)bh * LSEQ * ND;
    float*       ob = out + (size_t)bh * LSEQ * ND;

    const int row = tid >> 4;
    const int col = (tid & 15) * 4;
    const int t   = bt * 16 + row;

    float4 acc = make_float4(0.f, 0.f, 0.f, 0.f);
    #pragma unroll
    for (int kk = 0; kk < NDEL; ++kk) {
        const int r = (t + sd_[kk]) & (LSEQ - 1);
        const float4 vv = *(const float4*)(vb + (size_t)r * ND + col);
        const float wv = sw_[kk];
        acc.x += wv * vv.x; acc.y += wv * vv.y;
        acc.z += wv * vv.z; acc.w += wv * vv.w;
    }
    *(float4*)(ob + (size_t)t * ND + col) = acc;
}

// ---------------------------------------------------------------------------
extern "C" void kernel_launch(void* const* d_in, const int* in_sizes, int n_in,
                              void* d_out, int out_size, void* d_ws, size_t ws_size,
                              hipStream_t stream) {
    const float* q = (const float*)d_in[0];
    const float* k = (const float*)d_in[1];
    const float* v = (const float*)d_in[2];
    float* out = (float*)d_out;

    float2* P     = (float2*)((char*)d_ws + WS_P_OFF);
    float*  w     = (float*)((char*)d_ws + WS_W_OFF);
    int*    delay = (int*)((char*)d_ws + WS_DELAY_OFF);

    fft_corr<<<dim3(512), dim3(512), 0, stream>>>(q, k, P);
    reduce_S<<<dim3(64), dim3(256), 0, stream>>>(P);
    ifft_topk<<<dim3(NB), dim3(256), 0, stream>>>(P, w, delay);  // S = P[part 0]
    gather_out<<<dim3(NB * NH * 128), dim3(256), 0, stream>>>(v, w, delay, out);
}

// Round 3
// 209.450 us; speedup vs baseline: 1.9890x; 1.1076x over previous
//
#include <hip/hip_runtime.h>

// B=8, H=8, L=2048, D=64, num_delays=16
static constexpr int LSEQ = 2048;
static constexpr int NB   = 8;
static constexpr int NH   = 8;
static constexpr int ND   = 64;
static constexpr int NDEL = 16;

// ws layout (same 8.4 MB proven-safe envelope, same w/delay offsets):
//   Pc    : float2[128 part][8 b][1024]  at 0      (exactly 8 MiB)
//           compact partial spectra: slot j in [1,1024) holds freq j;
//           slot 0 packs (Re S[0], Re S[1024]) — both freqs are purely real.
//           After reduce_S, part 0 holds the reduced compact spectrum.
//   w     : float [8][16]               at 8388608
//   delay : int   [8][16]               at 8389120
static constexpr size_t WS_P_OFF     = 0;
static constexpr size_t WS_W_OFF     = 8388608;
static constexpr size_t WS_DELAY_OFF = 8389120;

// LDS bank swizzle on float2 index: fold bits 4..6 into bits 1..3.
__device__ __forceinline__ int SWZ(int x) { return x ^ (((x >> 4) & 7) << 1); }

// digit-reversed position of frequency f (radices 8,8,8,4 DIF) and inverse
__device__ __forceinline__ int pof(int f) {
    return ((f & 7) << 8) | (((f >> 3) & 7) << 5) | (((f >> 6) & 7) << 2) | (f >> 9);
}
__device__ __forceinline__ int fofp(int p) {
    return (p >> 8) | (((p >> 5) & 7) << 3) | (((p >> 2) & 7) << 6) | ((p & 3) << 9);
}

#define CMUL(ar, ai, br, bi) make_float2((ar)*(br) - (ai)*(bi), (ar)*(bi) + (ai)*(br))

// 8-pt DIF DFT in regs; x[0..7] in, X[0..7] (natural freq order) out.
__device__ __forceinline__ void dft8(const float2 x[8], float2 X[8]) {
    const float RH = 0.70710678118654752440f;
    float2 a0 = make_float2(x[0].x + x[4].x, x[0].y + x[4].y);
    float2 a1 = make_float2(x[1].x + x[5].x, x[1].y + x[5].y);
    float2 a2 = make_float2(x[2].x + x[6].x, x[2].y + x[6].y);
    float2 a3 = make_float2(x[3].x + x[7].x, x[3].y + x[7].y);
    float2 b0 = make_float2(x[0].x - x[4].x, x[0].y - x[4].y);
    float  t1r = x[1].x - x[5].x, t1i = x[1].y - x[5].y;
    float2 b1 = make_float2(RH * (t1r + t1i), RH * (t1i - t1r));       // * w8^1
    float  t2r = x[2].x - x[6].x, t2i = x[2].y - x[6].y;
    float2 b2 = make_float2(t2i, -t2r);                                // * -i
    float  t3r = x[3].x - x[7].x, t3i = x[3].y - x[7].y;
    float2 b3 = make_float2(RH * (t3i - t3r), -RH * (t3r + t3i));      // * w8^3
    float2 c0 = make_float2(a0.x + a2.x, a0.y + a2.y);
    float2 d0 = make_float2(a0.x - a2.x, a0.y - a2.y);
    float2 c1 = make_float2(a1.x + a3.x, a1.y + a3.y);
    float2 d1 = make_float2(a1.y - a3.y, -(a1.x - a3.x));              // * -i
    X[0] = make_float2(c0.x + c1.x, c0.y + c1.y);
    X[4] = make_float2(c0.x - c1.x, c0.y - c1.y);
    X[2] = make_float2(d0.x + d1.x, d0.y + d1.y);
    X[6] = make_float2(d0.x - d1.x, d0.y - d1.y);
    float2 e0 = make_float2(b0.x + b2.x, b0.y + b2.y);
    float2 f0 = make_float2(b0.x - b2.x, b0.y - b2.y);
    float2 e1 = make_float2(b1.x + b3.x, b1.y + b3.y);
    float2 f1 = make_float2(b1.y - b3.y, -(b1.x - b3.x));              // * -i
    X[1] = make_float2(e0.x + e1.x, e0.y + e1.y);
    X[5] = make_float2(e0.x - e1.x, e0.y - e1.y);
    X[3] = make_float2(f0.x + f1.x, f0.y + f1.y);
    X[7] = make_float2(f0.x - f1.x, f0.y - f1.y);
}

// 4-pt DFT: X[m] = sum_j x[j] (-i)^{jm}
__device__ __forceinline__ void dft4(const float2 x[4], float2 X[4]) {
    float2 s0 = make_float2(x[0].x + x[2].x, x[0].y + x[2].y);
    float2 s1 = make_float2(x[1].x + x[3].x, x[1].y + x[3].y);
    float2 d0 = make_float2(x[0].x - x[2].x, x[0].y - x[2].y);
    float2 d1 = make_float2(x[1].y - x[3].y, -(x[1].x - x[3].x));      // * -i
    X[0] = make_float2(s0.x + s1.x, s0.y + s1.y);
    X[2] = make_float2(s0.x - s1.x, s0.y - s1.y);
    X[1] = make_float2(d0.x + d1.x, d0.y + d1.y);
    X[3] = make_float2(d0.x - d1.x, d0.y - d1.y);
}

// in-place radix-8 stage with twiddle chain W on LDS plane zp
__device__ __forceinline__ void stageR8(float2* zp, const int adr[8], const float2 W[7]) {
    float2 X[8], Y[8];
    #pragma unroll
    for (int j = 0; j < 8; ++j) X[j] = zp[adr[j]];
    dft8(X, Y);
    #pragma unroll
    for (int m = 1; m < 8; ++m) Y[m] = CMUL(Y[m].x, Y[m].y, W[m-1].x, W[m-1].y);
    #pragma unroll
    for (int m = 0; m < 8; ++m) zp[adr[m]] = Y[m];
}

// final twiddle-free stage: two radix-4 on 8 consecutive; result also in X
__device__ __forceinline__ void stageD(float2* zp, const int adr[8], float2 X[8]) {
    float2 xin[8];
    #pragma unroll
    for (int j = 0; j < 8; ++j) xin[j] = zp[adr[j]];
    dft4(&xin[0], &X[0]);
    dft4(&xin[4], &X[4]);
    #pragma unroll
    for (int m = 0; m < 8; ++m) zp[adr[m]] = X[m];
}

// ---------------------------------------------------------------------------
// Kernel A: block = (b,h,grp of 8 d-chan, half of 4). Mixed-radix 8*8*8*4 DIF
// FFT, TWO channels in flight per sync phase (two 16 KiB LDS planes).
// Grid 1024 x 256 threads: the serial barrier chain is half of round-0's.
// __launch_bounds__(256,2) is the PROVEN no-spill config (VGPR=128; the
// round-1/2 (.,4) variants capped VGPR at 64 and spilled ~110 MB to scratch).
// At VGPR=128 + 32 KiB LDS the HW schedules 4 blocks/CU = 16 waves/CU = 2x
// round-0 occupancy, grid 1024 = exactly 4/CU. Store: COMPACT partial
// (f in [0,1024), slot 0 packs the two real freqs 0 and 1024) -> 128 private
// partials fit the same 8 MiB, no atomics, no races.
// ---------------------------------------------------------------------------
__global__ __launch_bounds__(256, 2) void fft_corr(const float* __restrict__ q,
                                                   const float* __restrict__ k,
                                                   float2* __restrict__ Pc) {
    __shared__ float2 z0[LSEQ], z1[LSEQ];   // 32 KiB (swizzled)
    const int t    = threadIdx.x;
    const int bi   = blockIdx.x;            // 1024 = 8 xcd * 8 bh * 8 grp * 2 half
    const int xcd  = bi & 7;
    const int sl   = bi >> 3;               // 0..127
    const int bh   = xcd * 8 + (sl >> 4);   // 16 blocks of same bh share an XCD
    const int grp  = (sl >> 1) & 7;
    const int half = sl & 1;
    const int b    = bh >> 3;
    const int h    = bh & 7;
    const size_t base = (size_t)bh * LSEQ * ND + (size_t)(grp * 8 + half * 4);

    // twiddle power chains (per thread, shared by all channels)
    float2 WA[7], WB[7], WC[7];
    {
        float sn, cs;
        __sincosf(-6.28318530717958647692f * (float)t / 2048.f, &sn, &cs);
        WA[0] = make_float2(cs, sn);
        __sincosf(-6.28318530717958647692f * (float)(t & 31) / 256.f, &sn, &cs);
        WB[0] = make_float2(cs, sn);
        __sincosf(-6.28318530717958647692f * (float)(t & 3) / 32.f, &sn, &cs);
        WC[0] = make_float2(cs, sn);
        #pragma unroll
        for (int m = 1; m < 7; ++m) {
            WA[m] = CMUL(WA[m-1].x, WA[m-1].y, WA[0].x, WA[0].y);
            WB[m] = CMUL(WB[m-1].x, WB[m-1].y, WB[0].x, WB[0].y);
            WC[m] = CMUL(WC[m-1].x, WC[m-1].y, WC[0].x, WC[0].y);
        }
    }

    // owned product slots: cc in {0,1,4,5} -> f in [0,1024)
    int fS[4], pmS[4];
    #pragma unroll
    for (int s = 0; s < 4; ++s) {
        const int cc = (s < 2) ? s : s + 2;           // {0,1,4,5}
        const int f  = fofp(8 * t + cc);
        const int m  = (2048 - f) & 2047;
        fS[s]  = f;
        pmS[s] = SWZ(pof(m));
    }
    float aFr[4] = {0, 0, 0, 0}, aFi[4] = {0, 0, 0, 0};
    float aS = 0.f;                      // f=1024 special (thread 0)

    const int sbB   = (t >> 5) * 256 + (t & 31);
    const int baseC = (t >> 2) * 32 + (t & 3);
    int adrB[8], adrC[8], adrD[8];
    #pragma unroll
    for (int n = 0; n < 8; ++n) {
        adrB[n] = SWZ(sbB + 32 * n);
        adrC[n] = SWZ(baseC + 4 * n);
        adrD[n] = SWZ(8 * t + n);
    }

    float4 qa[8], ka[8];
    #pragma unroll
    for (int j = 0; j < 8; ++j) {
        const size_t r = base + (size_t)(t + 256 * j) * ND;
        qa[j] = *(const float4*)(q + r);
        ka[j] = *(const float4*)(k + r);
    }
    #pragma unroll
    for (int pr = 0; pr < 2; ++pr) {
        const int c0 = 2 * pr, c1 = 2 * pr + 1;
        float2 X0[8], X1[8], Y0[8], Y1[8];
        #pragma unroll
        for (int j = 0; j < 8; ++j) {
            X0[j] = make_float2((&qa[j].x)[c0], (&ka[j].x)[c0]);
            X1[j] = make_float2((&qa[j].x)[c1], (&ka[j].x)[c1]);
        }
        __syncthreads();             // z planes free (prev pair's readers done)

        // stage A: radix-8 on rows t+256j (from regs), scatter to bands
        dft8(X0, Y0);
        dft8(X1, Y1);
        #pragma unroll
        for (int m = 1; m < 8; ++m) {
            Y0[m] = CMUL(Y0[m].x, Y0[m].y, WA[m-1].x, WA[m-1].y);
            Y1[m] = CMUL(Y1[m].x, Y1[m].y, WA[m-1].x, WA[m-1].y);
        }
        #pragma unroll
        for (int m = 0; m < 8; ++m) {
            const int a = SWZ(m * 256 + t);
            z0[a] = Y0[m];
            z1[a] = Y1[m];
        }
        __syncthreads();

        stageR8(z0, adrB, WB);
        stageR8(z1, adrB, WB);
        __syncthreads();

        stageR8(z0, adrC, WC);
        stageR8(z1, adrC, WC);
        __syncthreads();

        stageD(z0, adrD, X0);
        stageD(z1, adrD, X1);
        __syncthreads();

        // product: acc Q[f] conj(K[f]) for 4 owned slots (+f=1024)
        #pragma unroll
        for (int s = 0; s < 4; ++s) {
            const int cc = (s < 2) ? s : s + 2;   // {0,1,4,5}
            {
                const float2 Zf = X0[cc], Zm = z0[pmS[s]];
                const float qr = 0.5f * (Zf.x + Zm.x), qi = 0.5f * (Zf.y - Zm.y);
                const float kr = 0.5f * (Zf.y + Zm.y), ki = 0.5f * (Zm.x - Zf.x);
                aFr[s] += qr * kr + qi * ki;
                aFi[s] += qi * kr - qr * ki;
            }
            {
                const float2 Zf = X1[cc], Zm = z1[pmS[s]];
                const float qr = 0.5f * (Zf.x + Zm.x), qi = 0.5f * (Zf.y - Zm.y);
                const float kr = 0.5f * (Zf.y + Zm.y), ki = 0.5f * (Zm.x - Zf.x);
                aFr[s] += qr * kr + qi * ki;
                aFi[s] += qi * kr - qr * ki;
            }
        }
        if (t == 0) aS += X0[2].x * X0[2].y + X1[2].x * X1[2].y;
    }

    // compact store: Pc[part][b][f] = acc, f = fS[s] in [0,1024).
    // slot 0 packs (Re S[0], Re S[1024]); Im S[0] is mathematically 0.
    const int part = h * 16 + grp * 2 + half;        // 0..127
    float2* Pp = Pc + (size_t)part * (NB * 1024) + (size_t)b * 1024;
    #pragma unroll
    for (int s = 0; s < 4; ++s) Pp[fS[s]] = make_float2(aFr[s], aFi[s]);
    if (t == 0) Pp[0] = make_float2(aFr[0], aS);
}

// ---------------------------------------------------------------------------
// Reduce 128 compact partials IN-PLACE into part 0 (thread g owns column g —
// race-free). 32 blocks x 256 covers the 8 b x 1024 columns; 8 MiB read.
// ---------------------------------------------------------------------------
__global__ __launch_bounds__(256) void reduce_S(float2* __restrict__ Pc) {
    const int g = blockIdx.x * 256 + threadIdx.x;    // 0..8191 = b*1024+j
    float ax = 0.f, ay = 0.f;
    #pragma unroll 8
    for (int part = 0; part < 128; ++part) {
        const float2 v = Pc[(size_t)part * (NB * 1024) + g];
        ax += v.x; ay += v.y;
    }
    Pc[g] = make_float2(ax, ay);
}

// ---------------------------------------------------------------------------
// Kernel B: block per batch, 256 threads. Loads the COMPACT reduced spectrum
// (1024 float2), reconstructs the full conj-symmetric digit-rev spectrum in
// LDS, then inverse FFT via conj trick on the verified mixed-radix pipeline:
// irfft(S)[tau] = Re(FFT_fwd(conj(S))[tau])/N. 16-iter argmax top-k + softmax.
// ---------------------------------------------------------------------------
__global__ __launch_bounds__(256) void ifft_topk(const float2* __restrict__ S,
                                                 float* __restrict__ wout,
                                                 int* __restrict__ dout) {
    __shared__ float2 zz[LSEQ];          // 16 KiB work (swizzled in stages)
    __shared__ float  mc[LSEQ];          // 8 KiB, natural tau order
    __shared__ float  pv[4];
    __shared__ int    pig[4];
    __shared__ float  topv[NDEL];
    __shared__ int    topi[NDEL];
    const int b = blockIdx.x, t = threadIdx.x;

    float2 WA[7], WB[7], WC[7];
    {
        float sn, cs;
        __sincosf(-6.28318530717958647692f * (float)t / 2048.f, &sn, &cs);
        WA[0] = make_float2(cs, sn);
        __sincosf(-6.28318530717958647692f * (float)(t & 31) / 256.f, &sn, &cs);
        WB[0] = make_float2(cs, sn);
        __sincosf(-6.28318530717958647692f * (float)(t & 3) / 32.f, &sn, &cs);
        WC[0] = make_float2(cs, sn);
        #pragma unroll
        for (int m = 1; m < 7; ++m) {
            WA[m] = CMUL(WA[m-1].x, WA[m-1].y, WA[0].x, WA[0].y);
            WB[m] = CMUL(WB[m-1].x, WB[m-1].y, WB[0].x, WB[0].y);
            WC[m] = CMUL(WC[m-1].x, WC[m-1].y, WC[0].x, WC[0].y);
        }
    }
    const int sbB   = (t >> 5) * 256 + (t & 31);
    const int baseC = (t >> 2) * 32 + (t & 3);
    int adrB[8], adrC[8], adrD[8];
    #pragma unroll
    for (int n = 0; n < 8; ++n) {
        adrB[n] = SWZ(sbB + 32 * n);
        adrC[n] = SWZ(baseC + 4 * n);
        adrD[n] = SWZ(8 * t + n);
    }

    // load compact spectrum, reconstruct full digit-rev spectrum in zz:
    // freq j -> slot pof(j); freq 2048-j -> conj at slot pof(2048-j).
    #pragma unroll
    for (int u = 0; u < 4; ++u) {
        const int j = t + 256 * u;
        const float2 s = S[b * 1024 + j];
        if (j == 0) {
            zz[0] = make_float2(s.x, 0.f);            // pof(0)    = 0
            zz[2] = make_float2(s.y, 0.f);            // pof(1024) = 2
        } else {
            zz[pof(j)]        = s;
            zz[pof(2048 - j)] = make_float2(s.x, -s.y);
        }
    }
    __syncthreads();

    // gather stage-A operands: x[f] = conj(S[f]) at slot pof(f), f = t+256j
    float2 X[8], Y[8];
    #pragma unroll
    for (int j = 0; j < 8; ++j) {
        const float2 s = zz[pof(t + 256 * j)];
        X[j] = make_float2(s.x, -s.y);
    }
    __syncthreads();                     // all gathers done before scatter

    dft8(X, Y);
    #pragma unroll
    for (int m = 1; m < 8; ++m) Y[m] = CMUL(Y[m].x, Y[m].y, WA[m-1].x, WA[m-1].y);
    #pragma unroll
    for (int m = 0; m < 8; ++m) zz[SWZ(m * 256 + t)] = Y[m];
    __syncthreads();

    stageR8(zz, adrB, WB);
    __syncthreads();
    stageR8(zz, adrC, WC);
    __syncthreads();

    // stage D in regs only (no writeback needed)
    {
        float2 xin[8];
        #pragma unroll
        for (int j = 0; j < 8; ++j) xin[j] = zz[adrD[j]];
        dft4(&xin[0], &X[0]);
        dft4(&xin[4], &X[4]);
    }

    // mc[tau] = Re(out)/(L*H*D); slot 8t+cc holds tau = fofp(8t+cc)
    const float scale = 1.0f / ((float)LSEQ * (float)(NH * ND));
    #pragma unroll
    for (int cc = 0; cc < 8; ++cc) mc[fofp(8 * t + cc)] = X[cc].x * scale;
    __syncthreads();

    // top-16 by iterative argmax (ties -> smaller tau)
    const int lane = t & 63, wv = t >> 6;
    for (int it = 0; it < NDEL; ++it) {
        float bv = -3e38f; int bix = 0;
        #pragma unroll
        for (int u = 0; u < 8; ++u) {
            const int idx = t + 256 * u;
            const float v = mc[idx];
            if (v > bv || (v == bv && idx < bix)) { bv = v; bix = idx; }
        }
        #pragma unroll
        for (int off = 32; off; off >>= 1) {
            const float ov = __shfl_xor(bv, off);
            const int   oi = __shfl_xor(bix, off);
            if (ov > bv || (ov == bv && oi < bix)) { bv = ov; bix = oi; }
        }
        if (lane == 0) { pv[wv] = bv; pig[wv] = bix; }
        __syncthreads();
        if (t < 64) {
            float v = (t < 4) ? pv[t] : -3e38f;
            int  ii = (t < 4) ? pig[t] : 0;
            #pragma unroll
            for (int off = 2; off; off >>= 1) {
                const float ov = __shfl_xor(v, off);
                const int   oi = __shfl_xor(ii, off);
                if (ov > v || (ov == v && oi < ii)) { v = ov; ii = oi; }
            }
            if (t == 0) { topv[it] = v; topi[it] = ii; mc[ii] = -3e38f; }
        }
        __syncthreads();
    }

    if (t == 0) {
        const float m = topv[0];
        float e[NDEL], sum = 0.f;
        for (int i = 0; i < NDEL; ++i) { e[i] = __expf(topv[i] - m); sum += e[i]; }
        const float inv = 1.0f / sum;
        for (int i = 0; i < NDEL; ++i) {
            wout[b * NDEL + i] = e[i] * inv;
            dout[b * NDEL + i] = topi[i];
        }
    }
}

// ---------------------------------------------------------------------------
// Kernel C: out[b,h,t,d] = sum_k w[b,k] * v[b,h,(t+delay[b,k]) & 2047, d]
// XCD swizzle: 128 t-tiles of one (b,h) share an XCD (v slice L2-resident).
// ---------------------------------------------------------------------------
__global__ __launch_bounds__(256) void gather_out(const float* __restrict__ v,
                                                  const float* __restrict__ w,
                                                  const int* __restrict__ delay,
                                                  float* __restrict__ out) {
    const int bi  = blockIdx.x;          // 8192 = 64 bh * 128 tiles
    const int xcd = bi & 7;
    const int s   = bi >> 3;
    const int bh  = xcd * 8 + (s >> 7);
    const int bt  = s & 127;
    const int b   = bh >> 3;
    const int tid = threadIdx.x;

    __shared__ float sw_[NDEL];
    __shared__ int   sd_[NDEL];
    if (tid < NDEL) {
        sw_[tid] = w[b * NDEL + tid];
        sd_[tid] = delay[b * NDEL + tid];
    }
    __syncthreads();

    const float* vb = v + (size_t)bh * LSEQ * ND;
    float*       ob = out + (size_t)bh * LSEQ * ND;

    const int row = tid >> 4;
    const int col = (tid & 15) * 4;
    const int t   = bt * 16 + row;

    float4 acc = make_float4(0.f, 0.f, 0.f, 0.f);
    #pragma unroll
    for (int kk = 0; kk < NDEL; ++kk) {
        const int r = (t + sd_[kk]) & (LSEQ - 1);
        const float4 vv = *(const float4*)(vb + (size_t)r * ND + col);
        const float wv = sw_[kk];
        acc.x += wv * vv.x; acc.y += wv * vv.y;
        acc.z += wv * vv.z; acc.w += wv * vv.w;
    }
    *(float4*)(ob + (size_t)t * ND + col) = acc;
}

// ---------------------------------------------------------------------------
extern "C" void kernel_launch(void* const* d_in, const int* in_sizes, int n_in,
                              void* d_out, int out_size, void* d_ws, size_t ws_size,
                              hipStream_t stream) {
    const float* q = (const float*)d_in[0];
    const float* k = (const float*)d_in[1];
    const float* v = (const float*)d_in[2];
    float* out = (float*)d_out;

    float2* Pc    = (float2*)((char*)d_ws + WS_P_OFF);
    float*  w     = (float*)((char*)d_ws + WS_W_OFF);
    int*    delay = (int*)((char*)d_ws + WS_DELAY_OFF);

    fft_corr<<<dim3(1024), dim3(256), 0, stream>>>(q, k, Pc);
    reduce_S<<<dim3(32), dim3(256), 0, stream>>>(Pc);
    ifft_topk<<<dim3(NB), dim3(256), 0, stream>>>(Pc, w, delay);  // part 0 = S
    gather_out<<<dim3(NB * NH * 128), dim3(256), 0, stream>>>(v, w, delay, out);
}